// Round 11
// baseline (106.348 us; speedup 1.0000x reference)
//
#include <hip/hip_runtime.h>
#include <hip/hip_bf16.h>
#include <math.h>

#define NB   256
#define KIN  1024
#define ND   512
#define NP   2048
#define NTOT 4096   // Wm rows + proxy rows stacked

typedef __bf16 bf16x8 __attribute__((ext_vector_type(8)));
typedef float  f32x4  __attribute__((ext_vector_type(4)));
typedef unsigned short ush8 __attribute__((ext_vector_type(8)));

// ws byte offsets (16B aligned)
#define OFF_WPB    0u          // 4096*512 bf16 = 4 MB
#define OFF_FEAT32 4194304u    // 256*512 f32   = 512 KB
#define OFF_PN2    4718592u    // 2048 f32
#define OFF_LOGITS 4726784u    // 256*2048 f32  = 2 MB
#define OFF_SYNC   6823936u    // ticket + accum[2]

__device__ __forceinline__ ush8 pack8(float4 f0, float4 f1) {
    union { ush8 v; __hip_bfloat162 h[4]; } o;
    o.h[0] = __float22bfloat162_rn(make_float2(f0.x, f0.y));
    o.h[1] = __float22bfloat162_rn(make_float2(f0.z, f0.w));
    o.h[2] = __float22bfloat162_rn(make_float2(f1.x, f1.y));
    o.h[3] = __float22bfloat162_rn(make_float2(f1.z, f1.w));
    return o.v;
}
__device__ __forceinline__ float4 add4(float4 a, float4 b) {
    return make_float4(a.x + b.x, a.y + b.y, a.z + b.z, a.w + b.w);
}

// ---------------------------------------------------------------------------
// K0 (R7-identical): cast Wm+prox -> WPb bf16 + fused pn2 + zero feat32/sync.
// ---------------------------------------------------------------------------
__global__ __launch_bounds__(256) void k_prep(
    const float* __restrict__ Wm, const float* __restrict__ prox,
    unsigned short* __restrict__ WPb, float* __restrict__ pn2,
    float* __restrict__ feat32, unsigned* __restrict__ sync_area)
{
    const int t = threadIdx.x, lane = t & 63, w = t >> 6;
    if (t < 128) feat32[blockIdx.x * 128 + t] = 0.f;   // 1024*128 = 131072
    if (blockIdx.x == 0 && t == 0) {
        sync_area[0] = 0u;                  // ticket
        ((float*)sync_area)[4] = 0.f;       // accum[0]
        ((float*)sync_area)[5] = 0.f;       // accum[1]
    }
    const int r = blockIdx.x * 4 + w;      // 0..4095
    const float* src = (r < NP) ? (Wm + (size_t)r * ND)
                                : (prox + (size_t)(r - NP) * ND);
    float4 v0 = *(const float4*)(src + lane * 8);
    float4 v1 = *(const float4*)(src + lane * 8 + 4);
    *(ush8*)(WPb + (size_t)r * ND + lane * 8) = pack8(v0, v1);
    if (r >= NP) {
        float s = v0.x*v0.x + v0.y*v0.y + v0.z*v0.z + v0.w*v0.w
                + v1.x*v1.x + v1.y*v1.y + v1.z*v1.z + v1.w*v1.w;
#pragma unroll
        for (int off = 32; off; off >>= 1) s += __shfl_down(s, off);
        if (lane == 0) pn2[r - NP] = s;
    }
}

// ---------------------------------------------------------------------------
// K1 (R7-identical): feat GEMM split-K=8: feat32 += x @ Wb.T
// grid (8,4,8) = 256 blocks, 64x64 tile, K-chunk 128 = 4 steps of BK=32.
// ---------------------------------------------------------------------------
__global__ __launch_bounds__(256) void k_feat(
    const float* __restrict__ x, const float* __restrict__ Wb,
    float* __restrict__ feat32)
{
    __shared__ unsigned short As[2][64 * 32];
    __shared__ unsigned short Bs[2][64 * 32];
    const int t = threadIdx.x, lane = t & 63, w = t >> 6;
    const int n0 = blockIdx.x * 64, m0 = blockIdx.y * 64, k0 = blockIdx.z * 128;
    const int srow = t >> 2, sc = (t & 3) * 8;
    const float* gA = x  + (size_t)(m0 + srow) * KIN + k0 + sc;
    const float* gB = Wb + (size_t)(n0 + srow) * KIN + k0 + sc;
    float4 a0 = *(const float4*)gA, a1 = *(const float4*)(gA + 4);
    float4 b0 = *(const float4*)gB, b1 = *(const float4*)(gB + 4);
    f32x4 acc[2][2] = {};
    const int wm = (w >> 1) * 32, wn = (w & 1) * 32;
    const int arow = wm + (lane & 15), brow = wn + (lane & 15);
    const int fcol = (lane >> 4) * 8;
#pragma unroll
    for (int ks = 0; ks < 4; ++ks) {
        *(ush8*)&As[ks & 1][srow * 32 + sc] = pack8(a0, a1);
        *(ush8*)&Bs[ks & 1][srow * 32 + sc] = pack8(b0, b1);
        __syncthreads();
        if (ks + 1 < 4) {
            a0 = *(const float4*)(gA + (ks + 1) * 32);
            a1 = *(const float4*)(gA + (ks + 1) * 32 + 4);
            b0 = *(const float4*)(gB + (ks + 1) * 32);
            b1 = *(const float4*)(gB + (ks + 1) * 32 + 4);
        }
        const unsigned short* as = &As[ks & 1][0];
        const unsigned short* bs = &Bs[ks & 1][0];
        bf16x8 af0 = *(const bf16x8*)&as[(arow     ) * 32 + fcol];
        bf16x8 af1 = *(const bf16x8*)&as[(arow + 16) * 32 + fcol];
        bf16x8 bf0 = *(const bf16x8*)&bs[(brow     ) * 32 + fcol];
        bf16x8 bf1 = *(const bf16x8*)&bs[(brow + 16) * 32 + fcol];
        acc[0][0] = __builtin_amdgcn_mfma_f32_16x16x32_bf16(af0, bf0, acc[0][0], 0, 0, 0);
        acc[0][1] = __builtin_amdgcn_mfma_f32_16x16x32_bf16(af0, bf1, acc[0][1], 0, 0, 0);
        acc[1][0] = __builtin_amdgcn_mfma_f32_16x16x32_bf16(af1, bf0, acc[1][0], 0, 0, 0);
        acc[1][1] = __builtin_amdgcn_mfma_f32_16x16x32_bf16(af1, bf1, acc[1][1], 0, 0, 0);
    }
    const int q = lane >> 4, cn = lane & 15;
#pragma unroll
    for (int i = 0; i < 2; ++i)
#pragma unroll
        for (int j = 0; j < 2; ++j) {
            const int n = n0 + wn + 16 * j + cn;
#pragma unroll
            for (int r = 0; r < 4; ++r) {
                const int m = m0 + wm + 16 * i + q * 4 + r;
                atomicAdd(&feat32[m * ND + n], acc[i][j][r]);
            }
        }
}

// ---------------------------------------------------------------------------
// K2 (R7-identical): head GEMM 64x64 x (64,4)=256 blocks.
// A from fp32 feat32+bb (inline cvt); B bf16 from WPb.
//  n<2048: out = feat@Wm.T + bm ; n>=2048: logits = 2*feat@prox.T - pn2
// ---------------------------------------------------------------------------
__global__ __launch_bounds__(256) void k_head(
    const float* __restrict__ feat32, const float* __restrict__ bb,
    const unsigned short* __restrict__ WPb,
    const float* __restrict__ bm, const float* __restrict__ pn2,
    float* __restrict__ out, float* __restrict__ logits)
{
    __shared__ unsigned short As[2][64 * 32];
    __shared__ unsigned short Bs[2][64 * 32];
    const int t = threadIdx.x, lane = t & 63, w = t >> 6;
    const int n0 = blockIdx.x * 64;   // 64 n-tiles over 4096
    const int m0 = blockIdx.y * 64;   // 4 m-tiles over 256
    const int srow = t >> 2, sc = (t & 3) * 8;
    const float*          gA = feat32 + (size_t)(m0 + srow) * ND + sc;
    const unsigned short* gB = WPb    + (size_t)(n0 + srow) * ND + sc;
    float4 a0 = *(const float4*)gA, a1 = *(const float4*)(gA + 4);
    float4 u0 = *(const float4*)(bb + sc), u1 = *(const float4*)(bb + sc + 4);
    ush8 vb = *(const ush8*)gB;
    f32x4 acc[2][2] = {};
    const int wm = (w >> 1) * 32, wn = (w & 1) * 32;
    const int fr = lane & 15, fcol = (lane >> 4) * 8;
    for (int ks = 0; ks < ND / 32; ++ks) {
        *(ush8*)&As[ks & 1][srow * 32 + sc] = pack8(add4(a0, u0), add4(a1, u1));
        *(ush8*)&Bs[ks & 1][srow * 32 + sc] = vb;
        __syncthreads();
        if (ks + 1 < ND / 32) {
            a0 = *(const float4*)(gA + (ks + 1) * 32);
            a1 = *(const float4*)(gA + (ks + 1) * 32 + 4);
            u0 = *(const float4*)(bb + (ks + 1) * 32 + sc);
            u1 = *(const float4*)(bb + (ks + 1) * 32 + sc + 4);
            vb = *(const ush8*)(gB + (ks + 1) * 32);
        }
        const unsigned short* as = &As[ks & 1][0];
        const unsigned short* bs = &Bs[ks & 1][0];
        bf16x8 af0 = *(const bf16x8*)&as[(wm      + fr) * 32 + fcol];
        bf16x8 af1 = *(const bf16x8*)&as[(wm + 16 + fr) * 32 + fcol];
        bf16x8 bf0 = *(const bf16x8*)&bs[(wn      + fr) * 32 + fcol];
        bf16x8 bf1 = *(const bf16x8*)&bs[(wn + 16 + fr) * 32 + fcol];
        acc[0][0] = __builtin_amdgcn_mfma_f32_16x16x32_bf16(af0, bf0, acc[0][0], 0, 0, 0);
        acc[0][1] = __builtin_amdgcn_mfma_f32_16x16x32_bf16(af0, bf1, acc[0][1], 0, 0, 0);
        acc[1][0] = __builtin_amdgcn_mfma_f32_16x16x32_bf16(af1, bf0, acc[1][0], 0, 0, 0);
        acc[1][1] = __builtin_amdgcn_mfma_f32_16x16x32_bf16(af1, bf1, acc[1][1], 0, 0, 0);
    }
    const bool isProxy = (n0 >= NP);
    const int q = lane >> 4;
#pragma unroll
    for (int i = 0; i < 2; ++i)
#pragma unroll
        for (int j = 0; j < 2; ++j) {
            const int n = n0 + wn + 16 * j + fr;
            const float cadd = isProxy ? pn2[n - NP] : bm[n];
#pragma unroll
            for (int r = 0; r < 4; ++r) {
                const int m = m0 + wm + 16 * i + q * 4 + r;
                const float v = acc[i][j][r];
                if (isProxy) logits[m * NP + (n - NP)] = 2.0f * v - cadd;
                else         out[m * NP + n] = v + cadd;
            }
        }
}

__device__ __forceinline__ float block_reduce(float v, float* sred, int op)
{
    const int lane = threadIdx.x & 63, wave = threadIdx.x >> 6;
#pragma unroll
    for (int off = 32; off; off >>= 1) {
        float o = __shfl_down(v, off);
        v = op ? fmaxf(v, o) : (v + o);
    }
    if (lane == 0) sred[wave] = v;
    __syncthreads();
    if (threadIdx.x == 0) {
        float r = sred[0];
#pragma unroll
        for (int wv = 1; wv < 4; ++wv) r = op ? fmaxf(r, sred[wv]) : (r + sred[wv]);
        sred[0] = r;
    }
    __syncthreads();
    float r = sred[0];
    __syncthreads();
    return r;
}

// K3: per-row logsumexp + gather + feat row norm; ticket-merged final
// (the ONLY change vs R7: k_final folded in here).
__global__ __launch_bounds__(256) void k_loss(
    const float* __restrict__ feat32, const float* __restrict__ bb,
    const float* __restrict__ logits, const int* __restrict__ y,
    unsigned* __restrict__ sync_area, float* __restrict__ tail)
{
    __shared__ float sred[4];
    const int b = blockIdx.x, t = threadIdx.x;

    float v0 = feat32[b * ND + t] + bb[t];
    float v1 = feat32[b * ND + t + 256] + bb[t + 256];
    float fn2 = block_reduce(v0 * v0 + v1 * v1, sred, 0);

    const float* lr = logits + (size_t)b * NP;
    float lv[8], mx = -INFINITY;
#pragma unroll
    for (int j = 0; j < 8; ++j) { lv[j] = lr[t + 256 * j]; mx = fmaxf(mx, lv[j]); }
    float MX = block_reduce(mx, sred, 1);
    float es = 0.f;
#pragma unroll
    for (int j = 0; j < 8; ++j) es += __expf(lv[j] - MX);
    float SUM = block_reduce(es, sred, 0);

    if (t == 0) {
        float* accum = (float*)sync_area + 4;
        atomicAdd(&accum[0], lr[y[b]] - MX - __logf(SUM));
        atomicAdd(&accum[1], sqrtf(fn2));
        unsigned old = __hip_atomic_fetch_add(&sync_area[0], 1u,
                           __ATOMIC_ACQ_REL, __HIP_MEMORY_SCOPE_AGENT);
        if (old == NB - 1) {
            float s0 = __hip_atomic_load(&accum[0], __ATOMIC_RELAXED, __HIP_MEMORY_SCOPE_AGENT);
            float s1 = __hip_atomic_load(&accum[1], __ATOMIC_RELAXED, __HIP_MEMORY_SCOPE_AGENT);
            tail[0] = -s0 / (float)NB;
            tail[1] =  s1 / (float)NB;
        }
    }
}

extern "C" void kernel_launch(void* const* d_in, const int* in_sizes, int n_in,
                              void* d_out, int out_size, void* d_ws, size_t ws_size,
                              hipStream_t stream)
{
    const float* x       = (const float*)d_in[0];
    const int*   y       = (const int*)  d_in[1];
    const float* Wb      = (const float*)d_in[2];
    const float* bb      = (const float*)d_in[3];
    const float* Wm      = (const float*)d_in[4];
    const float* bm      = (const float*)d_in[5];
    const float* proxies = (const float*)d_in[6];

    char* ws = (char*)d_ws;
    unsigned short* WPb    = (unsigned short*)(ws + OFF_WPB);
    float*          feat32 = (float*)(ws + OFF_FEAT32);
    float*          pn2    = (float*)(ws + OFF_PN2);
    float*          logits = (float*)(ws + OFF_LOGITS);
    unsigned*       sync_a = (unsigned*)(ws + OFF_SYNC);

    float* out  = (float*)d_out;
    float* tail = out + (size_t)NB * NP;

    k_prep<<<dim3(NTOT / 4), dim3(256), 0, stream>>>(Wm, proxies, WPb, pn2, feat32, sync_a);
    k_feat<<<dim3(ND / 64, NB / 64, 8), dim3(256), 0, stream>>>(x, Wb, feat32);
    k_head<<<dim3(NTOT / 64, NB / 64), dim3(256), 0, stream>>>(
        feat32, bb, WPb, bm, pn2, out, logits);
    k_loss<<<dim3(NB), dim3(256), 0, stream>>>(feat32, bb, logits, y, sync_a, tail);
}

// Round 12
// 97.443 us; speedup vs baseline: 1.0914x; 1.0914x over previous
//
#include <hip/hip_runtime.h>
#include <hip/hip_bf16.h>
#include <math.h>

#define NB   256
#define KIN  1024
#define ND   512
#define NP   2048
#define NTOT 4096   // Wm rows + proxy rows stacked

typedef __bf16 bf16x8 __attribute__((ext_vector_type(8)));
typedef float  f32x4  __attribute__((ext_vector_type(4)));
typedef unsigned short ush8 __attribute__((ext_vector_type(8)));

// ws byte offsets (16B aligned)
#define OFF_WPB    0u          // 4096*512 bf16 = 4 MB
#define OFF_FEAT32 4194304u    // 256*512 f32   = 512 KB
#define OFF_PN2    4718592u    // 2048 f32
#define OFF_LOGITS 4726784u    // 256*2048 f32  = 2 MB
#define OFF_ROWLP  6823936u    // 256 f32
#define OFF_ROWNM  6824960u    // 256 f32

__device__ __forceinline__ ush8 pack8(float4 f0, float4 f1) {
    union { ush8 v; __hip_bfloat162 h[4]; } o;
    o.h[0] = __float22bfloat162_rn(make_float2(f0.x, f0.y));
    o.h[1] = __float22bfloat162_rn(make_float2(f0.z, f0.w));
    o.h[2] = __float22bfloat162_rn(make_float2(f1.x, f1.y));
    o.h[3] = __float22bfloat162_rn(make_float2(f1.z, f1.w));
    return o.v;
}
__device__ __forceinline__ float4 add4(float4 a, float4 b) {
    return make_float4(a.x + b.x, a.y + b.y, a.z + b.z, a.w + b.w);
}

// ---------------------------------------------------------------------------
// K0: cast Wm+prox -> WPb (bf16) + pn2 fused + zero feat32.
// 1024 blocks x 4 waves; wave w of block b owns row b*4+w.
// ---------------------------------------------------------------------------
__global__ __launch_bounds__(256) void k_prep(
    const float* __restrict__ Wm, const float* __restrict__ prox,
    unsigned short* __restrict__ WPb, float* __restrict__ pn2,
    float* __restrict__ feat32)
{
    const int t = threadIdx.x, lane = t & 63, w = t >> 6;
    if (t < 128) feat32[blockIdx.x * 128 + t] = 0.f;   // 1024*128 = 131072
    const int r = blockIdx.x * 4 + w;      // 0..4095
    const float* src = (r < NP) ? (Wm + (size_t)r * ND)
                                : (prox + (size_t)(r - NP) * ND);
    float4 v0 = *(const float4*)(src + lane * 8);
    float4 v1 = *(const float4*)(src + lane * 8 + 4);
    *(ush8*)(WPb + (size_t)r * ND + lane * 8) = pack8(v0, v1);
    if (r >= NP) {
        float s = v0.x*v0.x + v0.y*v0.y + v0.z*v0.z + v0.w*v0.w
                + v1.x*v1.x + v1.y*v1.y + v1.z*v1.z + v1.w*v1.w;
#pragma unroll
        for (int off = 32; off; off >>= 1) s += __shfl_down(s, off);
        if (lane == 0) pn2[r - NP] = s;
    }
}

// ---------------------------------------------------------------------------
// K1: feat GEMM split-K=8: feat32 += x @ Wb.T (no bias here).
// grid (8,4,8) = 256 blocks, 64x64 tile, K-chunk 128 = 4 steps of BK=32.
// ---------------------------------------------------------------------------
__global__ __launch_bounds__(256) void k_feat(
    const float* __restrict__ x, const float* __restrict__ Wb,
    float* __restrict__ feat32)
{
    __shared__ unsigned short As[2][64 * 32];
    __shared__ unsigned short Bs[2][64 * 32];
    const int t = threadIdx.x, lane = t & 63, w = t >> 6;
    const int n0 = blockIdx.x * 64, m0 = blockIdx.y * 64, k0 = blockIdx.z * 128;
    const int srow = t >> 2, sc = (t & 3) * 8;
    const float* gA = x  + (size_t)(m0 + srow) * KIN + k0 + sc;
    const float* gB = Wb + (size_t)(n0 + srow) * KIN + k0 + sc;
    float4 a0 = *(const float4*)gA, a1 = *(const float4*)(gA + 4);
    float4 b0 = *(const float4*)gB, b1 = *(const float4*)(gB + 4);
    f32x4 acc[2][2] = {};
    const int wm = (w >> 1) * 32, wn = (w & 1) * 32;
    const int arow = wm + (lane & 15), brow = wn + (lane & 15);
    const int fcol = (lane >> 4) * 8;
#pragma unroll
    for (int ks = 0; ks < 4; ++ks) {
        *(ush8*)&As[ks & 1][srow * 32 + sc] = pack8(a0, a1);
        *(ush8*)&Bs[ks & 1][srow * 32 + sc] = pack8(b0, b1);
        __syncthreads();
        if (ks + 1 < 4) {                  // prefetch flies under MFMAs
            a0 = *(const float4*)(gA + (ks + 1) * 32);
            a1 = *(const float4*)(gA + (ks + 1) * 32 + 4);
            b0 = *(const float4*)(gB + (ks + 1) * 32);
            b1 = *(const float4*)(gB + (ks + 1) * 32 + 4);
        }
        const unsigned short* as = &As[ks & 1][0];
        const unsigned short* bs = &Bs[ks & 1][0];
        bf16x8 af0 = *(const bf16x8*)&as[(arow     ) * 32 + fcol];
        bf16x8 af1 = *(const bf16x8*)&as[(arow + 16) * 32 + fcol];
        bf16x8 bf0 = *(const bf16x8*)&bs[(brow     ) * 32 + fcol];
        bf16x8 bf1 = *(const bf16x8*)&bs[(brow + 16) * 32 + fcol];
        acc[0][0] = __builtin_amdgcn_mfma_f32_16x16x32_bf16(af0, bf0, acc[0][0], 0, 0, 0);
        acc[0][1] = __builtin_amdgcn_mfma_f32_16x16x32_bf16(af0, bf1, acc[0][1], 0, 0, 0);
        acc[1][0] = __builtin_amdgcn_mfma_f32_16x16x32_bf16(af1, bf0, acc[1][0], 0, 0, 0);
        acc[1][1] = __builtin_amdgcn_mfma_f32_16x16x32_bf16(af1, bf1, acc[1][1], 0, 0, 0);
    }
    const int q = lane >> 4, cn = lane & 15;
#pragma unroll
    for (int i = 0; i < 2; ++i)
#pragma unroll
        for (int j = 0; j < 2; ++j) {
            const int n = n0 + wn + 16 * j + cn;
#pragma unroll
            for (int r = 0; r < 4; ++r) {
                const int m = m0 + wm + 16 * i + q * 4 + r;
                atomicAdd(&feat32[m * ND + n], acc[i][j][r]);
            }
        }
}

// ---------------------------------------------------------------------------
// K2: head GEMM, 64x64 tile x 256 blocks. A staged from fp32 feat32 + bb
// with inline bf16 cvt; B from bf16 WPb. dbuf + register prefetch.
//  n<2048: out = feat@Wm.T + bm ; n>=2048: logits = 2*feat@prox.T - pn2
// ---------------------------------------------------------------------------
__global__ __launch_bounds__(256) void k_head(
    const float* __restrict__ feat32, const float* __restrict__ bb,
    const unsigned short* __restrict__ WPb,
    const float* __restrict__ bm, const float* __restrict__ pn2,
    float* __restrict__ out, float* __restrict__ logits)
{
    __shared__ unsigned short As[2][64 * 32];
    __shared__ unsigned short Bs[2][64 * 32];
    const int t = threadIdx.x, lane = t & 63, w = t >> 6;
    const int n0 = blockIdx.x * 64;   // 64 n-tiles over 4096
    const int m0 = blockIdx.y * 64;   // 4 m-tiles over 256
    const int srow = t >> 2, sc = (t & 3) * 8;
    const float*          gA = feat32 + (size_t)(m0 + srow) * ND + sc;
    const unsigned short* gB = WPb    + (size_t)(n0 + srow) * ND + sc;
    float4 a0 = *(const float4*)gA, a1 = *(const float4*)(gA + 4);
    float4 u0 = *(const float4*)(bb + sc), u1 = *(const float4*)(bb + sc + 4);
    ush8 vb = *(const ush8*)gB;
    f32x4 acc[2][2] = {};
    const int wm = (w >> 1) * 32, wn = (w & 1) * 32;
    const int fr = lane & 15, fcol = (lane >> 4) * 8;
    for (int ks = 0; ks < ND / 32; ++ks) {
        *(ush8*)&As[ks & 1][srow * 32 + sc] = pack8(add4(a0, u0), add4(a1, u1));
        *(ush8*)&Bs[ks & 1][srow * 32 + sc] = vb;
        __syncthreads();
        if (ks + 1 < ND / 32) {
            a0 = *(const float4*)(gA + (ks + 1) * 32);
            a1 = *(const float4*)(gA + (ks + 1) * 32 + 4);
            u0 = *(const float4*)(bb + (ks + 1) * 32 + sc);
            u1 = *(const float4*)(bb + (ks + 1) * 32 + sc + 4);
            vb = *(const ush8*)(gB + (ks + 1) * 32);
        }
        const unsigned short* as = &As[ks & 1][0];
        const unsigned short* bs = &Bs[ks & 1][0];
        bf16x8 af0 = *(const bf16x8*)&as[(wm      + fr) * 32 + fcol];
        bf16x8 af1 = *(const bf16x8*)&as[(wm + 16 + fr) * 32 + fcol];
        bf16x8 bf0 = *(const bf16x8*)&bs[(wn      + fr) * 32 + fcol];
        bf16x8 bf1 = *(const bf16x8*)&bs[(wn + 16 + fr) * 32 + fcol];
        acc[0][0] = __builtin_amdgcn_mfma_f32_16x16x32_bf16(af0, bf0, acc[0][0], 0, 0, 0);
        acc[0][1] = __builtin_amdgcn_mfma_f32_16x16x32_bf16(af0, bf1, acc[0][1], 0, 0, 0);
        acc[1][0] = __builtin_amdgcn_mfma_f32_16x16x32_bf16(af1, bf0, acc[1][0], 0, 0, 0);
        acc[1][1] = __builtin_amdgcn_mfma_f32_16x16x32_bf16(af1, bf1, acc[1][1], 0, 0, 0);
    }
    const bool isProxy = (n0 >= NP);
    const int q = lane >> 4;
#pragma unroll
    for (int i = 0; i < 2; ++i)
#pragma unroll
        for (int j = 0; j < 2; ++j) {
            const int n = n0 + wn + 16 * j + fr;
            const float cadd = isProxy ? pn2[n - NP] : bm[n];
#pragma unroll
            for (int r = 0; r < 4; ++r) {
                const int m = m0 + wm + 16 * i + q * 4 + r;
                const float v = acc[i][j][r];
                if (isProxy) logits[m * NP + (n - NP)] = 2.0f * v - cadd;
                else         out[m * NP + n] = v + cadd;
            }
        }
}

__device__ __forceinline__ float block_reduce(float v, float* sred, int op)
{
    const int lane = threadIdx.x & 63, wave = threadIdx.x >> 6;
#pragma unroll
    for (int off = 32; off; off >>= 1) {
        float o = __shfl_down(v, off);
        v = op ? fmaxf(v, o) : (v + o);
    }
    if (lane == 0) sred[wave] = v;
    __syncthreads();
    if (threadIdx.x == 0) {
        float r = sred[0];
#pragma unroll
        for (int wv = 1; wv < 4; ++wv) r = op ? fmaxf(r, sred[wv]) : (r + sred[wv]);
        sred[0] = r;
    }
    __syncthreads();
    float r = sred[0];
    __syncthreads();
    return r;
}

// K3: per-row logsumexp + gather + feat row norm (fp32 feat + bias)
__global__ __launch_bounds__(256) void k_loss(
    const float* __restrict__ feat32, const float* __restrict__ bb,
    const float* __restrict__ logits, const int* __restrict__ y,
    float* __restrict__ rowlp, float* __restrict__ rownm)
{
    __shared__ float sred[4];
    const int b = blockIdx.x, t = threadIdx.x;

    float v0 = feat32[b * ND + t] + bb[t];
    float v1 = feat32[b * ND + t + 256] + bb[t + 256];
    float fn2 = block_reduce(v0 * v0 + v1 * v1, sred, 0);

    const float* lr = logits + (size_t)b * NP;
    float lv[8], mx = -INFINITY;
#pragma unroll
    for (int j = 0; j < 8; ++j) { lv[j] = lr[t + 256 * j]; mx = fmaxf(mx, lv[j]); }
    float MX = block_reduce(mx, sred, 1);
    float es = 0.f;
#pragma unroll
    for (int j = 0; j < 8; ++j) es += __expf(lv[j] - MX);
    float SUM = block_reduce(es, sred, 0);

    if (t == 0) {
        float ly = lr[y[b]];
        rowlp[b] = ly - MX - __logf(SUM);
        rownm[b] = sqrtf(fn2);
    }
}

// K4: final 256-wide reduction -> (loss, reg_e)
__global__ __launch_bounds__(256) void k_final(
    const float* __restrict__ rowlp, const float* __restrict__ rownm,
    float* __restrict__ tail)
{
    __shared__ float sred[4];
    const int t = threadIdx.x;
    float s1 = block_reduce(rowlp[t], sred, 0);
    float s2 = block_reduce(rownm[t], sred, 0);
    if (t == 0) {
        tail[0] = -s1 / (float)NB;
        tail[1] =  s2 / (float)NB;
    }
}

extern "C" void kernel_launch(void* const* d_in, const int* in_sizes, int n_in,
                              void* d_out, int out_size, void* d_ws, size_t ws_size,
                              hipStream_t stream)
{
    const float* x       = (const float*)d_in[0];
    const int*   y       = (const int*)  d_in[1];
    const float* Wb      = (const float*)d_in[2];
    const float* bb      = (const float*)d_in[3];
    const float* Wm      = (const float*)d_in[4];
    const float* bm      = (const float*)d_in[5];
    const float* proxies = (const float*)d_in[6];

    char* ws = (char*)d_ws;
    unsigned short* WPb    = (unsigned short*)(ws + OFF_WPB);
    float*          feat32 = (float*)(ws + OFF_FEAT32);
    float*          pn2    = (float*)(ws + OFF_PN2);
    float*          logits = (float*)(ws + OFF_LOGITS);
    float*          rowlp  = (float*)(ws + OFF_ROWLP);
    float*          rownm  = (float*)(ws + OFF_ROWNM);

    float* out  = (float*)d_out;
    float* tail = out + (size_t)NB * NP;

    k_prep <<<dim3(NTOT / 4), dim3(256), 0, stream>>>(Wm, proxies, WPb, pn2, feat32);
    k_feat <<<dim3(ND / 64, NB / 64, 8), dim3(256), 0, stream>>>(x, Wb, feat32);
    k_head <<<dim3(NTOT / 64, NB / 64), dim3(256), 0, stream>>>(
        feat32, bb, WPb, bm, pn2, out, logits);
    k_loss <<<dim3(NB), dim3(256), 0, stream>>>(feat32, bb, logits, y, rowlp, rownm);
    k_final<<<dim3(1), dim3(256), 0, stream>>>(rowlp, rownm, tail);
}